// Round 11
// baseline (104.077 us; speedup 1.0000x reference)
//
#include <hip/hip_runtime.h>
#include <math.h>

namespace {
constexpr int kH = 512;
constexpr int kN = 64;
constexpr int kL = 4096;
constexpr int kM = 2048;      // L/2
constexpr int kPairRec = 40;  // floats per n-PAIR record (160 B)
constexpr int kThreads = 512;
constexpr float kPi = 3.14159265358979323846f;
}

typedef float v2f __attribute__((ext_vector_type(2)));

__device__ __forceinline__ int lpad(int i) { return i + (i >> 4); }
__device__ __forceinline__ float2 cmul(float2 a, float2 b) {
    return make_float2(a.x*b.x - a.y*b.y, a.x*b.y + a.y*b.x);
}

// ---- forced VOP3P packed-fp32 helpers (R11 experiment) ----
// Theory: VALUBusy(63%) matches the SCALAR-fma instruction model (2x the
// packed model) -> compiler is not forming v_pk_*_f32 from v2f arithmetic.
// These wrappers force it. Coefficients come from wave-uniform s_load and
// are bound "s" (SGPR-pair source -- exactly one SGPR operand per
// instruction, legal); accumulators are tied in-place with "+v".
__device__ __forceinline__ v2f pk_sub_vs(v2f s, v2f v) {   // v - s
    v2f d;
    asm("v_pk_add_f32 %0, %1, %2 neg_lo:[1,0] neg_hi:[1,0]"
        : "=v"(d) : "s"(s), "v"(v));
    return d;
}
__device__ __forceinline__ v2f pk_add_sv(v2f s, v2f v) {   // v + s
    v2f d;
    asm("v_pk_add_f32 %0, %1, %2" : "=v"(d) : "s"(s), "v"(v));
    return d;
}
__device__ __forceinline__ v2f pk_fma_vvs(v2f a, v2f b, v2f cs) {  // a*b + cs
    v2f d;
    asm("v_pk_fma_f32 %0, %1, %2, %3" : "=v"(d) : "v"(a), "v"(b), "s"(cs));
    return d;
}
__device__ __forceinline__ v2f pk_mul_vv(v2f a, v2f b) {
    v2f d;
    asm("v_pk_mul_f32 %0, %1, %2" : "=v"(d) : "v"(a), "v"(b));
    return d;
}
__device__ __forceinline__ void pk_fma_acc_sv(v2f& acc, v2f cs, v2f b) {
    // acc += cs * b   (cs from SGPR pair, acc tied in place)
    asm("v_pk_fma_f32 %0, %1, %2, %0" : "+v"(acc) : "s"(cs), "v"(b));
}

// ===================== Kernel 0: prep =====================
// One 64-thread block per head (blockIdx = h). Writes pair-interleaved
// coefficient records to GLOBAL cst (consumed via wave-uniform s_load --
// R9: scalar path beats VMEM broadcast by 2x). Spare lanes (tid<8) build
// the block-invariant trig tables (ttab/wtab/ztab, 4097 float2 total)
// so the consumer has zero sincos/div (R10).
//   s_r(l) = sum_n (a0 + a1*s)/D        s = 4t^2, t = tan(pi*l/L)
//   s_i(l) = t * sum_n (b0 + b1*s)/D    D = m1*m2, m = ar^2 + (2t -+ ai)^2
//   (D in PRODUCT form: polynomial-in-s cancels at resonances)
//   a0 = -2*C1*(vr*ar + vi*ai)          a1 = 2*(vi*ai - vr*ar)
//   b0 = -4*vr*(ar^2-ai^2) - 8*vi*ar*ai b1 = -4*vr       [C1 = ar^2+ai^2]
__global__ __launch_bounds__(64)
void s4_prep(const float* __restrict__ A_real, const float* __restrict__ A_imag,
             const float* __restrict__ Bv, const float* __restrict__ Cv,
             const float* __restrict__ Pv, const float* __restrict__ inv_dt,
             float* __restrict__ cst, float* __restrict__ xnyq,
             float2* __restrict__ ttab, float2* __restrict__ wtab,
             float2* __restrict__ ztab)
{
    const int h = blockIdx.x;
    const int n = threadIdx.x;

    // ---- block-invariant tables (8 entries per block) ----
    if (n < 8) {
        const int e = (h << 3) | n;          // 0..4095
        if (e < kM) {                        // ttab[l] = {t, 4t^2}
            float s, c;
            sincosf((float)e * (kPi / (float)kL), &s, &c);
            const float t = s / c;
            ttab[e] = make_float2(t, 4.f * t * t);
        } else if (e < kM + kM/2) {          // wtab[j] = e^{+2pi i j/2048}
            const int j = e - kM;
            float s, c;
            sincosf((2.0f * kPi / (float)kM) * (float)j, &s, &c);
            wtab[j] = make_float2(c, s);
        } else {                             // ztab[k] = e^{+2pi i k/4096}, k<1024
            const int k2 = e - (kM + kM/2);
            float s, c;
            sincosf((2.0f * kPi / (float)kL) * (float)k2, &s, &c);
            ztab[k2] = make_float2(c, s);
        }
    }
    if (h == 0 && n == 8) ztab[kM/2] = make_float2(0.0f, 1.0f);  // e^{i pi/2}

    const int idx = h * kN + n;
    const float dt = expf(inv_dt[h]);
    const float ar = -expf(A_real[idx]) * dt;   // Re(A*dt) (negative)
    const float ai =  A_imag[idx] * dt;         // Im(A*dt)
    const float br = Bv[idx*2+0], bi = Bv[idx*2+1];
    const float cr = Cv[idx*2+0], ci = Cv[idx*2+1];
    const float pr = Pv[idx*2+0], pi = Pv[idx*2+1];
    const float v00r = (br*cr - bi*ci)*dt, v00i = (br*ci + bi*cr)*dt;  // B*C
    const float v01r = (br*pr + bi*pi)*dt, v01i = (bi*pr - br*pi)*dt;  // B*conj(P)
    const float v10r = (pr*cr - pi*ci)*dt, v10i = (pr*ci + pi*cr)*dt;  // P*C
    const float v11r = (pr*pr + pi*pi)*dt;                              // |P|^2 (real)
    const float ar2 = ar*ar;
    const float C1  = ar2 + ai*ai;
    const float dd  = ar2 - ai*ai;

    float co[16];
    co[0]  = -2.f*C1*(v00r*ar + v00i*ai);   co[1]  = 2.f*(v00i*ai - v00r*ar);
    co[2]  = -4.f*v00r*dd - 8.f*v00i*ar*ai; co[3]  = -4.f*v00r;
    co[4]  = -2.f*C1*(v01r*ar + v01i*ai);   co[5]  = 2.f*(v01i*ai - v01r*ar);
    co[6]  = -4.f*v01r*dd - 8.f*v01i*ar*ai; co[7]  = -4.f*v01r;
    co[8]  = -2.f*C1*(v10r*ar + v10i*ai);   co[9]  = 2.f*(v10i*ai - v10r*ar);
    co[10] = -4.f*v10r*dd - 8.f*v10i*ar*ai; co[11] = -4.f*v10r;
    co[12] = -2.f*C1*(v11r*ar);             co[13] = -2.f*v11r*ar;
    co[14] = -4.f*v11r*dd;                  co[15] = -4.f*v11r;

    float* base = cst + ((size_t)h * (kN/2) + (n >> 1)) * kPairRec + (n & 1);
    base[0] = ai;
    base[2] = ar2;
    #pragma unroll
    for (int k = 0; k < 16; ++k) base[4 + 2*k] = co[k];
    // floats 36..39 unused padding

    // Nyquist (u=0): k_f[2048] = sum_n Re(B*C)*dt (real); block = one wave
    float s = v00r;
    #pragma unroll
    for (int off = 32; off > 0; off >>= 1) s += __shfl_down(s, off, 64);
    if (n == 0) xnyq[h] = s;
}

// ===================== Kernel 1: fused spectrum + irfft =====================
// One 512-thread block per head; __launch_bounds__(512, 4) = 2 blocks/CU.
// R10 structure (best: 41.4 us): s_load coefficients, 2 passes x 2
// bins/thread, folded accumulation, ONE rcp per n-pair per bin, precomputed
// trig tables. ONLY change vs R10: the spectrum inner loop's packed ops are
// forced to VOP3P (v_pk_*_f32) via inline asm -- the VALUBusy arithmetic
// (26 us issue vs 11-13 us packed model) says the compiler was emitting
// SCALAR v_fma pairs. If this lands, spectrum issue halves.
// X[l] lands in LDS; then the packed-real 2048-pt inverse complex DFT runs
// in the same block (radix-4 fused DIT passes, first pass twiddle-free,
// lpad(i)=i+(i>>4) bank-conflict padding).
// LDS: XS 16 KB + W2 17.4 KB + TW 8.7 KB = ~42.1 KB -> 2 blocks/CU.
__global__ __launch_bounds__(kThreads, 4)
void s4_spec_ifft(const float* __restrict__ cst, const float* __restrict__ xnyq,
                  const float2* __restrict__ ttab, const float2* __restrict__ wtab,
                  const float2* __restrict__ ztab, float* __restrict__ out)
{
    __shared__ float2 XS[kM];                    // spectrum output X[l], linear
    __shared__ float2 W2[kM + kM / 16];
    __shared__ float2 TW[kM / 2 + kM / 32];

    const int h   = blockIdx.x;
    const int tid = threadIdx.x;

    // twiddle table from global (consumed only after >=2 later barriers)
    for (int j = tid; j < kM / 2; j += kThreads) {
        TW[lpad(j)] = wtab[j];                 // e^{+2pi i j / 2048}
    }

    // ---------------- spectrum phase ----------------
    const v2f* rec = (const v2f*)(cst + (size_t)h * (kN/2) * kPairRec);
    #pragma unroll 1
    for (int pass = 0; pass < 2; ++pass) {
        const int la = pass * 1024 + tid;      // bins la and la+512

        float tvb[2];
        v2f t2p[2], spv[2];
        #pragma unroll
        for (int bb = 0; bb < 2; ++bb) {
            const int l = la + 512 * bb;
            const float2 ts = ttab[l];         // {tan(pi*l/L), 4t^2}
            tvb[bb] = ts.x;
            const float t2 = ts.x + ts.x;
            t2p[bb] = (v2f){t2, t2};
            spv[bb] = (v2f){ts.y, ts.y};
        }

        // [bin][product {00,01,10,11}] packed partial sums (16 live v2f):
        // accR += c0*qv + c1*(s*qv) ; accI += c2*qv + c3*(s*qv)
        v2f accR[2][4], accI[2][4];
        #pragma unroll
        for (int bb = 0; bb < 2; ++bb)
            #pragma unroll
            for (int p = 0; p < 4; ++p) {
                accR[bb][p] = (v2f){0.f, 0.f};
                accI[bb][p] = (v2f){0.f, 0.f};
            }

        #pragma unroll 2
        for (int j = 0; j < kN/2; ++j) {
            const v2f* r = rec + j * (kPairRec/2);   // wave-uniform -> s_load
            const v2f aip  = r[0];
            const v2f ar2p = r[1];
            #pragma unroll
            for (int bb = 0; bb < 2; ++bb) {
                const v2f w1 = pk_sub_vs(aip, t2p[bb]);      // t2 - aip
                const v2f w2 = pk_add_sv(aip, t2p[bb]);      // t2 + aip
                const v2f m1 = pk_fma_vvs(w1, w1, ar2p);
                const v2f m2 = pk_fma_vvs(w2, w2, ar2p);
                const v2f D  = pk_mul_vv(m1, m2);
                const float qq = __builtin_amdgcn_rcpf(D.x * D.y);
                v2f qv;
                qv.x = D.y * qq;
                qv.y = D.x * qq;
                const v2f sqv = pk_mul_vv(spv[bb], qv);      // shared across products
                #pragma unroll
                for (int p = 0; p < 4; ++p) {
                    pk_fma_acc_sv(accR[bb][p], r[2 + 4*p + 0], qv);
                    pk_fma_acc_sv(accR[bb][p], r[2 + 4*p + 1], sqv);
                    pk_fma_acc_sv(accI[bb][p], r[2 + 4*p + 2], qv);
                    pk_fma_acc_sv(accI[bb][p], r[2 + 4*p + 3], sqv);
                }
            }
        }

        #pragma unroll
        for (int bb = 0; bb < 2; ++bb) {
            const int l = la + 512 * bb;
            const float t = tvb[bb];
            const float s00r = accR[bb][0].x + accR[bb][0].y;
            const float s00i = t * (accI[bb][0].x + accI[bb][0].y);
            const float s01r = accR[bb][1].x + accR[bb][1].y;
            const float s01i = t * (accI[bb][1].x + accI[bb][1].y);
            const float s10r = accR[bb][2].x + accR[bb][2].y;
            const float s10i = t * (accI[bb][2].x + accI[bb][2].y);
            const float s11r = accR[bb][3].x + accR[bb][3].y;
            const float s11i = t * (accI[bb][3].x + accI[bb][3].y);
            const float nr = s01r*s10r - s01i*s10i;
            const float ni = s01r*s10i + s01i*s10r;
            const float dr = 1.f + s11r, di = s11i;
            const float qd = __builtin_amdgcn_rcpf(fmaf(dr, dr, di*di));
            const float wr = (nr*dr + ni*di) * qd;
            const float wi = (ni*dr - nr*di) * qd;
            const float gr = s00r - wr, gi = s00i - wi;
            // k_f = g * (1 + i*t)
            XS[l] = make_float2(fmaf(-gi, t, gr), fmaf(gr, t, gi));
        }
    }
    __syncthreads();

    // ---------------- irfft phase ----------------
    // build Z (bit-reversed) from LDS X:
    // E = (X[k]+conj(X[M-k]))/2 ; O = e^{+2pi i k/L}*(X[k]-conj(X[M-k]))/2
    // Z[k] = (Er-Oi, Ei+Or); Z[M-k] = (Er+Oi, Or-Ei)
    const float nyqR = xnyq[h];
    for (int k = tid; k <= kM / 2; k += kThreads) {
        const float2 Xa = XS[k];
        const float2 Xb = (k == 0) ? make_float2(nyqR, 0.0f) : XS[kM - k];
        const float Er = 0.5f * (Xa.x + Xb.x);
        const float Ei = 0.5f * (Xa.y - Xb.y);
        const float Dr = 0.5f * (Xa.x - Xb.x);
        const float Di = 0.5f * (Xa.y + Xb.y);
        const float2 zc = ztab[k];             // e^{+2pi i k / L}
        const float Or = zc.x * Dr - zc.y * Di;
        const float Oi = zc.x * Di + zc.y * Dr;
        const int rk = (int)(__brev((unsigned)k) >> 21);          // 11-bit reversal
        W2[lpad(rk)] = make_float2(Er - Oi, Ei + Or);
        if (k != 0 && k != kM / 2) {
            const int rmk = (int)(__brev((unsigned)(kM - k)) >> 21);
            W2[lpad(rmk)] = make_float2(Er + Oi, Or - Ei);
        }
    }
    __syncthreads();

    // first radix-4 pass (hs=1): wB = wA = 1 -- no twiddle loads, no cmuls
    for (int j = tid; j < kM / 4; j += kThreads) {
        const int i0 = j * 4;
        const float2 e0 = W2[lpad(i0)];
        const float2 e1 = W2[lpad(i0 + 1)];
        const float2 e2 = W2[lpad(i0 + 2)];
        const float2 e3 = W2[lpad(i0 + 3)];
        const float2 a0 = make_float2(e0.x + e1.x, e0.y + e1.y);
        const float2 a1 = make_float2(e0.x - e1.x, e0.y - e1.y);
        const float2 a2 = make_float2(e2.x + e3.x, e2.y + e3.y);
        const float2 a3 = make_float2(e2.x - e3.x, e2.y - e3.y);
        W2[lpad(i0)]     = make_float2(a0.x + a2.x, a0.y + a2.y);
        W2[lpad(i0 + 2)] = make_float2(a0.x - a2.x, a0.y - a2.y);
        W2[lpad(i0 + 1)] = make_float2(a1.x - a3.y, a1.y + a3.x);  // a1 + i*a3
        W2[lpad(i0 + 3)] = make_float2(a1.x + a3.y, a1.y - a3.x);  // a1 - i*a3
    }
    __syncthreads();

    // remaining fused radix-4 passes: stages (hs, 2hs) for hs = 4,16,64,256
    #pragma unroll
    for (int lg = 2; lg <= 8; lg += 2) {
        const int hs = 1 << lg;
        const int twstride = 512 >> lg;      // 512/hs
        for (int j = tid; j < kM / 4; j += kThreads) {
            const int pos = j & (hs - 1);
            const int grp = j >> lg;
            const int i0  = grp * 4 * hs + pos;
            const float2 e0 = W2[lpad(i0)];
            const float2 e1 = W2[lpad(i0 + hs)];
            const float2 e2 = W2[lpad(i0 + 2*hs)];
            const float2 e3 = W2[lpad(i0 + 3*hs)];
            const float2 wB = TW[lpad(pos * twstride)];
            const float2 wA = cmul(wB, wB);
            const float2 t1 = cmul(wA, e1);
            const float2 t3 = cmul(wA, e3);
            const float2 a0 = make_float2(e0.x + t1.x, e0.y + t1.y);
            const float2 a1 = make_float2(e0.x - t1.x, e0.y - t1.y);
            const float2 a2 = make_float2(e2.x + t3.x, e2.y + t3.y);
            const float2 a3 = make_float2(e2.x - t3.x, e2.y - t3.y);
            const float2 u2 = cmul(wB, a2);
            const float2 u3 = cmul(wB, a3);
            W2[lpad(i0)]        = make_float2(a0.x + u2.x, a0.y + u2.y);
            W2[lpad(i0 + 2*hs)] = make_float2(a0.x - u2.x, a0.y - u2.y);
            W2[lpad(i0 + hs)]   = make_float2(a1.x - u3.y, a1.y + u3.x);  // a1 + i*u3
            W2[lpad(i0 + 3*hs)] = make_float2(a1.x + u3.y, a1.y - u3.x);  // a1 - i*u3
        }
        __syncthreads();
    }
    // final radix-2 stage, hs = 1024
    for (int j = tid; j < kM / 2; j += kThreads) {
        const float2 tw = TW[lpad(j)];
        const float2 a  = W2[lpad(j)];
        const float2 b  = W2[lpad(j + 1024)];
        const float2 tb = cmul(tw, b);
        W2[lpad(j)]        = make_float2(a.x + tb.x, a.y + tb.y);
        W2[lpad(j + 1024)] = make_float2(a.x - tb.x, a.y - tb.y);
    }
    __syncthreads();

    const float invM = 1.0f / (float)kM;
    float2* out2 = (float2*)(out + (size_t)h * kL);
    for (int n = tid; n < kM; n += kThreads) {
        const float2 zn = W2[lpad(n)];
        out2[n] = make_float2(zn.x * invM, zn.y * invM);
    }
}

extern "C" void kernel_launch(void* const* d_in, const int* in_sizes, int n_in,
                              void* d_out, int out_size, void* d_ws, size_t ws_size,
                              hipStream_t stream) {
    const float* A_real = (const float*)d_in[0];
    const float* A_imag = (const float*)d_in[1];
    const float* B      = (const float*)d_in[2];
    const float* C      = (const float*)d_in[3];
    const float* P      = (const float*)d_in[4];
    const float* inv_dt = (const float*)d_in[5];
    float* out = (float*)d_out;

    float*  cst  = (float*)d_ws;                       // 512*32*40 floats = 2.62 MB
    float*  xnyq = cst + (size_t)kH * (kN/2) * kPairRec;   // 512 floats
    float2* ttab = (float2*)(xnyq + kH);               // 2048 float2
    float2* wtab = ttab + kM;                          // 1024 float2
    float2* ztab = wtab + kM/2;                        // 1025 float2

    s4_prep<<<dim3(kH), dim3(64), 0, stream>>>(A_real, A_imag, B, C, P, inv_dt,
                                               cst, xnyq, ttab, wtab, ztab);
    s4_spec_ifft<<<dim3(kH), dim3(kThreads), 0, stream>>>(cst, xnyq, ttab, wtab,
                                                          ztab, out);
}

// Round 12
// 101.976 us; speedup vs baseline: 1.0206x; 1.0206x over previous
//
#include <hip/hip_runtime.h>
#include <math.h>

namespace {
constexpr int kH = 512;
constexpr int kN = 64;
constexpr int kL = 4096;
constexpr int kM = 2048;      // L/2
constexpr int kPairRec = 40;  // floats per n-PAIR record (160 B)
constexpr int kThreads = 512;
constexpr float kPi = 3.14159265358979323846f;
}

typedef float v2f __attribute__((ext_vector_type(2)));

__device__ __forceinline__ int lpad(int i) { return i + (i >> 4); }
__device__ __forceinline__ float2 cmul(float2 a, float2 b) {
    return make_float2(a.x*b.x - a.y*b.y, a.x*b.y + a.y*b.x);
}

// ---- VOP3P packed-fp32 helpers (R11) ----
// R11 verified these compile & pass. NOTE (R11 lesson): v_pk_*_f32 has NO
// throughput gain on gfx950 (FP32 peak 157 TF has no packed doubling) --
// their purpose here is NOT speed per op but the "+v" TIE on accumulators:
// inline asm cannot be loop-distributed/rematerialized, which is what
// defeated every >16-accumulator variant (R1/R3/R4). Coefficients bound
// "s" (SGPR pair from wave-uniform s_load; exactly 1 scalar operand/instr).
__device__ __forceinline__ v2f pk_sub_vs(v2f s, v2f v) {   // v - s
    v2f d;
    asm("v_pk_add_f32 %0, %1, %2 neg_lo:[1,0] neg_hi:[1,0]"
        : "=v"(d) : "s"(s), "v"(v));
    return d;
}
__device__ __forceinline__ v2f pk_add_sv(v2f s, v2f v) {   // v + s
    v2f d;
    asm("v_pk_add_f32 %0, %1, %2" : "=v"(d) : "s"(s), "v"(v));
    return d;
}
__device__ __forceinline__ v2f pk_fma_vvs(v2f a, v2f b, v2f cs) {  // a*b + cs
    v2f d;
    asm("v_pk_fma_f32 %0, %1, %2, %3" : "=v"(d) : "v"(a), "v"(b), "s"(cs));
    return d;
}
__device__ __forceinline__ v2f pk_mul_vv(v2f a, v2f b) {
    v2f d;
    asm("v_pk_mul_f32 %0, %1, %2" : "=v"(d) : "v"(a), "v"(b));
    return d;
}
__device__ __forceinline__ void pk_fma_acc_sv(v2f& acc, v2f cs, v2f b) {
    // acc += cs * b   (cs from SGPR pair, acc tied in place -- unsplittable)
    asm("v_pk_fma_f32 %0, %1, %2, %0" : "+v"(acc) : "s"(cs), "v"(b));
}

// ===================== Kernel 0: prep =====================
// One 64-thread block per head (blockIdx = h). Writes pair-interleaved
// coefficient records to GLOBAL cst (consumed via wave-uniform s_load --
// R9: scalar path beats VMEM broadcast by 2x). Spare lanes (tid<8) build
// the block-invariant trig tables (ttab/wtab/ztab, 4097 float2 total)
// so the consumer has zero sincos/div (R10).
//   s_r(l) = sum_n (a0 + a1*s)/D        s = 4t^2, t = tan(pi*l/L)
//   s_i(l) = t * sum_n (b0 + b1*s)/D    D = m1*m2, m = ar^2 + (2t -+ ai)^2
//   (D in PRODUCT form: polynomial-in-s cancels at resonances)
//   a0 = -2*C1*(vr*ar + vi*ai)          a1 = 2*(vi*ai - vr*ar)
//   b0 = -4*vr*(ar^2-ai^2) - 8*vi*ar*ai b1 = -4*vr       [C1 = ar^2+ai^2]
__global__ __launch_bounds__(64)
void s4_prep(const float* __restrict__ A_real, const float* __restrict__ A_imag,
             const float* __restrict__ Bv, const float* __restrict__ Cv,
             const float* __restrict__ Pv, const float* __restrict__ inv_dt,
             float* __restrict__ cst, float* __restrict__ xnyq,
             float2* __restrict__ ttab, float2* __restrict__ wtab,
             float2* __restrict__ ztab)
{
    const int h = blockIdx.x;
    const int n = threadIdx.x;

    // ---- block-invariant tables (8 entries per block) ----
    if (n < 8) {
        const int e = (h << 3) | n;          // 0..4095
        if (e < kM) {                        // ttab[l] = {t, 4t^2}
            float s, c;
            sincosf((float)e * (kPi / (float)kL), &s, &c);
            const float t = s / c;
            ttab[e] = make_float2(t, 4.f * t * t);
        } else if (e < kM + kM/2) {          // wtab[j] = e^{+2pi i j/2048}
            const int j = e - kM;
            float s, c;
            sincosf((2.0f * kPi / (float)kM) * (float)j, &s, &c);
            wtab[j] = make_float2(c, s);
        } else {                             // ztab[k] = e^{+2pi i k/4096}, k<1024
            const int k2 = e - (kM + kM/2);
            float s, c;
            sincosf((2.0f * kPi / (float)kL) * (float)k2, &s, &c);
            ztab[k2] = make_float2(c, s);
        }
    }
    if (h == 0 && n == 8) ztab[kM/2] = make_float2(0.0f, 1.0f);  // e^{i pi/2}

    const int idx = h * kN + n;
    const float dt = expf(inv_dt[h]);
    const float ar = -expf(A_real[idx]) * dt;   // Re(A*dt) (negative)
    const float ai =  A_imag[idx] * dt;         // Im(A*dt)
    const float br = Bv[idx*2+0], bi = Bv[idx*2+1];
    const float cr = Cv[idx*2+0], ci = Cv[idx*2+1];
    const float pr = Pv[idx*2+0], pi = Pv[idx*2+1];
    const float v00r = (br*cr - bi*ci)*dt, v00i = (br*ci + bi*cr)*dt;  // B*C
    const float v01r = (br*pr + bi*pi)*dt, v01i = (bi*pr - br*pi)*dt;  // B*conj(P)
    const float v10r = (pr*cr - pi*ci)*dt, v10i = (pr*ci + pi*cr)*dt;  // P*C
    const float v11r = (pr*pr + pi*pi)*dt;                              // |P|^2 (real)
    const float ar2 = ar*ar;
    const float C1  = ar2 + ai*ai;
    const float dd  = ar2 - ai*ai;

    float co[16];
    co[0]  = -2.f*C1*(v00r*ar + v00i*ai);   co[1]  = 2.f*(v00i*ai - v00r*ar);
    co[2]  = -4.f*v00r*dd - 8.f*v00i*ar*ai; co[3]  = -4.f*v00r;
    co[4]  = -2.f*C1*(v01r*ar + v01i*ai);   co[5]  = 2.f*(v01i*ai - v01r*ar);
    co[6]  = -4.f*v01r*dd - 8.f*v01i*ar*ai; co[7]  = -4.f*v01r;
    co[8]  = -2.f*C1*(v10r*ar + v10i*ai);   co[9]  = 2.f*(v10i*ai - v10r*ar);
    co[10] = -4.f*v10r*dd - 8.f*v10i*ar*ai; co[11] = -4.f*v10r;
    co[12] = -2.f*C1*(v11r*ar);             co[13] = -2.f*v11r*ar;
    co[14] = -4.f*v11r*dd;                  co[15] = -4.f*v11r;

    float* base = cst + ((size_t)h * (kN/2) + (n >> 1)) * kPairRec + (n & 1);
    base[0] = ai;
    base[2] = ar2;
    #pragma unroll
    for (int k = 0; k < 16; ++k) base[4 + 2*k] = co[k];
    // floats 36..39 unused padding

    // Nyquist (u=0): k_f[2048] = sum_n Re(B*C)*dt (real); block = one wave
    float s = v00r;
    #pragma unroll
    for (int off = 32; off > 0; off >>= 1) s += __shfl_down(s, off, 64);
    if (n == 0) xnyq[h] = s;
}

// ===================== Kernel 1: fused spectrum + irfft =====================
// One 512-thread block per head; __launch_bounds__(512, 4) = 2 blocks/CU.
// KEY CHANGE vs R10/R11: SINGLE-PASS spectrum, 4 bins/thread -- each
// coefficient record is s_loaded ONCE (was twice) and feeds 4 bins' worth
// of compute (~420 cyc/record vs ~200), so the ~900-cyc HBM first-touch
// latency of the cst stream (FETCH_SIZE ~ full 2.6 MB, zero inter-block
// reuse) is covered. The 32 v2f accumulators that made the compiler
// loop-distribute this exact structure in R1 are now PINNED via R11's
// inline-asm "+v" ties -- asm can't be split or rematerialized.
// VALU floor note (R11): v_pk_f32 has no throughput gain on gfx950; the
// spectrum's ~25 us of issue is the arithmetic floor -- this round attacks
// the 42% stall fraction, not the issue count.
// X[l] lands in LDS; then the packed-real 2048-pt inverse complex DFT runs
// in the same block (radix-4 fused DIT passes, first pass twiddle-free,
// lpad(i)=i+(i>>4) bank-conflict padding). Trig from precomputed tables.
// LDS: XS 16 KB + W2 17.4 KB + TW 8.7 KB = ~42.1 KB -> 2 blocks/CU.
__global__ __launch_bounds__(kThreads, 4)
void s4_spec_ifft(const float* __restrict__ cst, const float* __restrict__ xnyq,
                  const float2* __restrict__ ttab, const float2* __restrict__ wtab,
                  const float2* __restrict__ ztab, float* __restrict__ out)
{
    __shared__ float2 XS[kM];                    // spectrum output X[l], linear
    __shared__ float2 W2[kM + kM / 16];
    __shared__ float2 TW[kM / 2 + kM / 32];

    const int h   = blockIdx.x;
    const int tid = threadIdx.x;

    // twiddle table from global (consumed only after >=2 later barriers)
    for (int j = tid; j < kM / 2; j += kThreads) {
        TW[lpad(j)] = wtab[j];                 // e^{+2pi i j / 2048}
    }

    // ---------------- spectrum phase: single pass, 4 bins/thread ----------
    const v2f* rec = (const v2f*)(cst + (size_t)h * (kN/2) * kPairRec);

    v2f t2p[4], spv[4];
    #pragma unroll
    for (int bb = 0; bb < 4; ++bb) {
        const int l = bb * 512 + tid;
        const float2 ts = ttab[l];             // {tan(pi*l/L), 4t^2}
        const float t2 = ts.x + ts.x;
        t2p[bb] = (v2f){t2, t2};
        spv[bb] = (v2f){ts.y, ts.y};
    }

    // [bin][product {00,01,10,11}] packed partial sums -- 32 v2f (64 VGPR),
    // pinned by asm ties; accR += c0*qv + c1*(s*qv), accI += c2*qv + c3*(s*qv)
    v2f accR[4][4], accI[4][4];
    #pragma unroll
    for (int bb = 0; bb < 4; ++bb)
        #pragma unroll
        for (int p = 0; p < 4; ++p) {
            accR[bb][p] = (v2f){0.f, 0.f};
            accI[bb][p] = (v2f){0.f, 0.f};
        }

    #pragma unroll 2
    for (int j = 0; j < kN/2; ++j) {
        const v2f* r = rec + j * (kPairRec/2);   // wave-uniform -> s_load
        const v2f aip  = r[0];
        const v2f ar2p = r[1];
        #pragma unroll
        for (int bb = 0; bb < 4; ++bb) {
            const v2f w1 = pk_sub_vs(aip, t2p[bb]);      // t2 - aip
            const v2f w2 = pk_add_sv(aip, t2p[bb]);      // t2 + aip
            const v2f m1 = pk_fma_vvs(w1, w1, ar2p);
            const v2f m2 = pk_fma_vvs(w2, w2, ar2p);
            const v2f D  = pk_mul_vv(m1, m2);
            const float qq = __builtin_amdgcn_rcpf(D.x * D.y);
            v2f qv;
            qv.x = D.y * qq;
            qv.y = D.x * qq;
            const v2f sqv = pk_mul_vv(spv[bb], qv);      // shared across products
            #pragma unroll
            for (int p = 0; p < 4; ++p) {
                pk_fma_acc_sv(accR[bb][p], r[2 + 4*p + 0], qv);
                pk_fma_acc_sv(accR[bb][p], r[2 + 4*p + 1], sqv);
                pk_fma_acc_sv(accI[bb][p], r[2 + 4*p + 2], qv);
                pk_fma_acc_sv(accI[bb][p], r[2 + 4*p + 3], sqv);
            }
        }
    }

    #pragma unroll
    for (int bb = 0; bb < 4; ++bb) {
        const int l = bb * 512 + tid;
        const float t = 0.5f * t2p[bb].x;
        const float s00r = accR[bb][0].x + accR[bb][0].y;
        const float s00i = t * (accI[bb][0].x + accI[bb][0].y);
        const float s01r = accR[bb][1].x + accR[bb][1].y;
        const float s01i = t * (accI[bb][1].x + accI[bb][1].y);
        const float s10r = accR[bb][2].x + accR[bb][2].y;
        const float s10i = t * (accI[bb][2].x + accI[bb][2].y);
        const float s11r = accR[bb][3].x + accR[bb][3].y;
        const float s11i = t * (accI[bb][3].x + accI[bb][3].y);
        const float nr = s01r*s10r - s01i*s10i;
        const float ni = s01r*s10i + s01i*s10r;
        const float dr = 1.f + s11r, di = s11i;
        const float qd = __builtin_amdgcn_rcpf(fmaf(dr, dr, di*di));
        const float wr = (nr*dr + ni*di) * qd;
        const float wi = (ni*dr - nr*di) * qd;
        const float gr = s00r - wr, gi = s00i - wi;
        // k_f = g * (1 + i*t)
        XS[l] = make_float2(fmaf(-gi, t, gr), fmaf(gr, t, gi));
    }
    __syncthreads();

    // ---------------- irfft phase ----------------
    // build Z (bit-reversed) from LDS X:
    // E = (X[k]+conj(X[M-k]))/2 ; O = e^{+2pi i k/L}*(X[k]-conj(X[M-k]))/2
    // Z[k] = (Er-Oi, Ei+Or); Z[M-k] = (Er+Oi, Or-Ei)
    const float nyqR = xnyq[h];
    for (int k = tid; k <= kM / 2; k += kThreads) {
        const float2 Xa = XS[k];
        const float2 Xb = (k == 0) ? make_float2(nyqR, 0.0f) : XS[kM - k];
        const float Er = 0.5f * (Xa.x + Xb.x);
        const float Ei = 0.5f * (Xa.y - Xb.y);
        const float Dr = 0.5f * (Xa.x - Xb.x);
        const float Di = 0.5f * (Xa.y + Xb.y);
        const float2 zc = ztab[k];             // e^{+2pi i k / L}
        const float Or = zc.x * Dr - zc.y * Di;
        const float Oi = zc.x * Di + zc.y * Dr;
        const int rk = (int)(__brev((unsigned)k) >> 21);          // 11-bit reversal
        W2[lpad(rk)] = make_float2(Er - Oi, Ei + Or);
        if (k != 0 && k != kM / 2) {
            const int rmk = (int)(__brev((unsigned)(kM - k)) >> 21);
            W2[lpad(rmk)] = make_float2(Er + Oi, Or - Ei);
        }
    }
    __syncthreads();

    // first radix-4 pass (hs=1): wB = wA = 1 -- no twiddle loads, no cmuls
    for (int j = tid; j < kM / 4; j += kThreads) {
        const int i0 = j * 4;
        const float2 e0 = W2[lpad(i0)];
        const float2 e1 = W2[lpad(i0 + 1)];
        const float2 e2 = W2[lpad(i0 + 2)];
        const float2 e3 = W2[lpad(i0 + 3)];
        const float2 a0 = make_float2(e0.x + e1.x, e0.y + e1.y);
        const float2 a1 = make_float2(e0.x - e1.x, e0.y - e1.y);
        const float2 a2 = make_float2(e2.x + e3.x, e2.y + e3.y);
        const float2 a3 = make_float2(e2.x - e3.x, e2.y - e3.y);
        W2[lpad(i0)]     = make_float2(a0.x + a2.x, a0.y + a2.y);
        W2[lpad(i0 + 2)] = make_float2(a0.x - a2.x, a0.y - a2.y);
        W2[lpad(i0 + 1)] = make_float2(a1.x - a3.y, a1.y + a3.x);  // a1 + i*a3
        W2[lpad(i0 + 3)] = make_float2(a1.x + a3.y, a1.y - a3.x);  // a1 - i*a3
    }
    __syncthreads();

    // remaining fused radix-4 passes: stages (hs, 2hs) for hs = 4,16,64,256
    #pragma unroll
    for (int lg = 2; lg <= 8; lg += 2) {
        const int hs = 1 << lg;
        const int twstride = 512 >> lg;      // 512/hs
        for (int j = tid; j < kM / 4; j += kThreads) {
            const int pos = j & (hs - 1);
            const int grp = j >> lg;
            const int i0  = grp * 4 * hs + pos;
            const float2 e0 = W2[lpad(i0)];
            const float2 e1 = W2[lpad(i0 + hs)];
            const float2 e2 = W2[lpad(i0 + 2*hs)];
            const float2 e3 = W2[lpad(i0 + 3*hs)];
            const float2 wB = TW[lpad(pos * twstride)];
            const float2 wA = cmul(wB, wB);
            const float2 t1 = cmul(wA, e1);
            const float2 t3 = cmul(wA, e3);
            const float2 a0 = make_float2(e0.x + t1.x, e0.y + t1.y);
            const float2 a1 = make_float2(e0.x - t1.x, e0.y - t1.y);
            const float2 a2 = make_float2(e2.x + t3.x, e2.y + t3.y);
            const float2 a3 = make_float2(e2.x - t3.x, e2.y - t3.y);
            const float2 u2 = cmul(wB, a2);
            const float2 u3 = cmul(wB, a3);
            W2[lpad(i0)]        = make_float2(a0.x + u2.x, a0.y + u2.y);
            W2[lpad(i0 + 2*hs)] = make_float2(a0.x - u2.x, a0.y - u2.y);
            W2[lpad(i0 + hs)]   = make_float2(a1.x - u3.y, a1.y + u3.x);  // a1 + i*u3
            W2[lpad(i0 + 3*hs)] = make_float2(a1.x + u3.y, a1.y - u3.x);  // a1 - i*u3
        }
        __syncthreads();
    }
    // final radix-2 stage, hs = 1024
    for (int j = tid; j < kM / 2; j += kThreads) {
        const float2 tw = TW[lpad(j)];
        const float2 a  = W2[lpad(j)];
        const float2 b  = W2[lpad(j + 1024)];
        const float2 tb = cmul(tw, b);
        W2[lpad(j)]        = make_float2(a.x + tb.x, a.y + tb.y);
        W2[lpad(j + 1024)] = make_float2(a.x - tb.x, a.y - tb.y);
    }
    __syncthreads();

    const float invM = 1.0f / (float)kM;
    float2* out2 = (float2*)(out + (size_t)h * kL);
    for (int n = tid; n < kM; n += kThreads) {
        const float2 zn = W2[lpad(n)];
        out2[n] = make_float2(zn.x * invM, zn.y * invM);
    }
}

extern "C" void kernel_launch(void* const* d_in, const int* in_sizes, int n_in,
                              void* d_out, int out_size, void* d_ws, size_t ws_size,
                              hipStream_t stream) {
    const float* A_real = (const float*)d_in[0];
    const float* A_imag = (const float*)d_in[1];
    const float* B      = (const float*)d_in[2];
    const float* C      = (const float*)d_in[3];
    const float* P      = (const float*)d_in[4];
    const float* inv_dt = (const float*)d_in[5];
    float* out = (float*)d_out;

    float*  cst  = (float*)d_ws;                       // 512*32*40 floats = 2.62 MB
    float*  xnyq = cst + (size_t)kH * (kN/2) * kPairRec;   // 512 floats
    float2* ttab = (float2*)(xnyq + kH);               // 2048 float2
    float2* wtab = ttab + kM;                          // 1024 float2
    float2* ztab = wtab + kM/2;                        // 1025 float2

    s4_prep<<<dim3(kH), dim3(64), 0, stream>>>(A_real, A_imag, B, C, P, inv_dt,
                                               cst, xnyq, ttab, wtab, ztab);
    s4_spec_ifft<<<dim3(kH), dim3(kThreads), 0, stream>>>(cst, xnyq, ttab, wtab,
                                                          ztab, out);
}